// Round 7
// baseline (1170.434 us; speedup 1.0000x reference)
//
#include <hip/hip_runtime.h>

#define Bq 2
#define Lq 1024
#define Dq 128
#define Vq 5

typedef __attribute__((ext_vector_type(4))) float float4v;

// ws layout (floats): [0,640) P1b  [640,1280) P2  [1280] x-dtype flag (int)
#define WS_FLAG_OFF 1280

// ---------------------------------------------------------------------------
// Kernel 0: x dtype insurance. int64 x -> odd int32 words all zero -> flag 0.
// int32 x -> odd words are random 0..4 -> flag nonzero w.p. 1 - 5^-1024.
// ---------------------------------------------------------------------------
__global__ void k_flag(const int* __restrict__ x32, int* __restrict__ flag) {
    __shared__ int red[256];
    const int t = threadIdx.x;
    int acc = 0;
    for (int k = t; k < 1024; k += 256)
        acc |= x32[2 * k + 1];
    red[t] = acc;
    __syncthreads();
    for (int s = 128; s > 0; s >>= 1) {
        if (t < s) red[t] |= red[t + s];
        __syncthreads();
    }
    if (t == 0) flag[0] = red[0];
}

__device__ __forceinline__ int x_at(const int* __restrict__ x32, int f, int idx) {
    return x32[f ? idx : 2 * idx];   // f!=0: int32; f==0: int64 low word
}

// ---------------------------------------------------------------------------
// Kernel 1: blocks [0,5)   -> P1b[v][e] = sum_d emb[v,d]*W[e,d] + bias[e]
//                             P2 [v][e] = sum_d emb[v,d]*W[e,D+d]
//           blocks [5,133) -> s gather (fp32): s[b,l,:] = emb[x[b,l],:]
// ---------------------------------------------------------------------------
__global__ void k_prep(const int* __restrict__ x32,
                       const float* __restrict__ emb,
                       const float* __restrict__ W,
                       const float* __restrict__ bias,
                       float* __restrict__ ws,
                       float* __restrict__ s_out) {
    const int bid = blockIdx.x;
    const int t   = threadIdx.x;
    if (bid < Vq) {
        const int v     = bid;
        const int which = t >> 7;     // 0 -> P1 (+bias), 1 -> P2
        const int e     = t & 127;
        float acc = which ? 0.0f : bias[e];
        const float* wrow = W + e * (2 * Dq) + which * Dq;
        const float* erow = emb + v * Dq;
        #pragma unroll 8
        for (int d = 0; d < Dq; ++d)
            acc += erow[d] * wrow[d];
        ws[which * (Vq * Dq) + v * Dq + e] = acc;
    } else {
        const int f    = ((const int*)ws)[WS_FLAG_OFF];
        const int sb   = bid - Vq;            // 0..127
        const int pair = t >> 4;              // 0..15
        const int dgrp = t & 15;              // 0..15
        const int bl   = sb * 16 + pair;      // flat (b,l), 0..2047
        const int v    = x_at(x32, f, bl);
        const float* src = emb + v * Dq + dgrp * 8;
        float*       dst = s_out + (size_t)bl * Dq + dgrp * 8;
        float4v a = *reinterpret_cast<const float4v*>(src);
        float4v b = *reinterpret_cast<const float4v*>(src + 4);
        *reinterpret_cast<float4v*>(dst)     = a;
        *reinterpret_cast<float4v*>(dst + 4) = b;
    }
}

__device__ __forceinline__ float sel5(const float p[5], int v) {
    float p_ = p[4];
    p_ = (v == 3) ? p[3] : p_;
    p_ = (v == 2) ? p[2] : p_;
    p_ = (v == 1) ? p[1] : p_;
    p_ = (v == 0) ? p[0] : p_;
    return p_;
}

// ---------------------------------------------------------------------------
// Kernel 2 (R7): grid-stride ROW SWEEP. Global row g = (b*128+e)*1024 + l1,
// g in [0, 262144). Block n at iteration i writes row g = i*2048 + n
// (one 4-KB row: thread t -> cols 4t..4t+3). All 2048 blocks are resident,
// so each iteration the machine writes a compact, contiguous 8-MB window
// that advances in address order — mimicking fillBuffer's frontier
// (R6's per-block 512-KB chunks = 8192 scattered 4-KB-strided streams,
// suspected DRAM row-buffer thrash at exactly 1/2 BW).
// Since 2048 % 1024 == 0: l1 = n & 1023 is block-constant; (b,e) sweep:
// e = 2*i2 + (n>>10), b = half. P columns reloaded per iter (L1-hot 5 KB).
// ---------------------------------------------------------------------------
__global__ void __launch_bounds__(256) k_m(const int* __restrict__ x32,
                                           const float* __restrict__ ws,
                                           float* __restrict__ m_out) {
    const int n  = blockIdx.x;          // 0..2047
    const int t  = threadIdx.x;         // 0..255, cols 4t..4t+3
    const int f  = ((const int*)ws)[WS_FLAG_OFF];
    const int l1 = n & 1023;
    const int hi = n >> 10;             // e parity

    // tokens (block/thread-constant)
    const int v1a = x_at(x32, f, l1);        // c1 token, b=0
    const int v1b = x_at(x32, f, Lq + l1);   // c1 token, b=1
    int va[4], vb[4];
    #pragma unroll
    for (int j = 0; j < 4; ++j) {
        va[j] = x_at(x32, f, 4 * t + j);
        vb[j] = x_at(x32, f, Lq + 4 * t + j);
    }

    const float* __restrict__ P1 = ws;         // [v*128 + e]
    const float* __restrict__ P2 = ws + Vq * Dq;

    #pragma unroll
    for (int half = 0; half < 2; ++half) {   // half == b
        const int tok1 = half ? v1b : v1a;
        int tj[4];
        #pragma unroll
        for (int j = 0; j < 4; ++j) tj[j] = half ? vb[j] : va[j];

        #pragma unroll 4
        for (int i2 = 0; i2 < 64; ++i2) {
            const int i = half * 64 + i2;
            const int e = 2 * i2 + hi;                  // (2i+hi) & 127
            float p1c[5], p2c[5];
            #pragma unroll
            for (int v = 0; v < 5; ++v) {
                p1c[v] = P1[v * Dq + e];
                p2c[v] = P2[v * Dq + e];
            }
            const float c1 = sel5(p1c, tok1);
            float4v o;
            #pragma unroll
            for (int j = 0; j < 4; ++j)
                o[j] = c1 + sel5(p2c, tj[j]);
            const size_t g = (size_t)i * 2048 + n;
            *reinterpret_cast<float4v*>(m_out + g * Lq + 4 * t) = o;
        }
    }
}

extern "C" void kernel_launch(void* const* d_in, const int* in_sizes, int n_in,
                              void* d_out, int out_size, void* d_ws, size_t ws_size,
                              hipStream_t stream) {
    const int*   x32  = (const int*)d_in[0];    // int32 (int64 auto-handled)
    const float* emb  = (const float*)d_in[1];
    const float* W    = (const float*)d_in[2];
    const float* bias = (const float*)d_in[3];
    float* out   = (float*)d_out;               // fp32 output buffer
    float* ws    = (float*)d_ws;
    float* s_out = out;
    float* m_out = out + (size_t)Bq * Lq * Dq;

    k_flag<<<1, 256, 0, stream>>>(x32, ((int*)ws) + WS_FLAG_OFF);
    k_prep<<<Vq + (Bq * Lq / 16), 256, 0, stream>>>(x32, emb, W, bias, ws, s_out);
    k_m<<<Bq * Dq * (Lq / 128), 256, 0, stream>>>(x32, ws, m_out);  // 2048 blocks
}

// Round 8
// 1085.915 us; speedup vs baseline: 1.0778x; 1.0778x over previous
//
#include <hip/hip_runtime.h>

#define Bq 2
#define Lq 1024
#define Dq 128
#define Vq 5

typedef __attribute__((ext_vector_type(4))) float float4v;
typedef __attribute__((ext_vector_type(4))) int   int4v;

// ws layout (floats): [0,640) P1b  [640,1280) P2  [1280] flag(int)
//                     [2048, 2048+262144) c1T[b][e][l1]
#define WS_FLAG_OFF 1280
#define WS_C1_OFF   2048

// ---------------------------------------------------------------------------
// Kernel 0: x dtype insurance (int32 vs int64 low-word layout).
// ---------------------------------------------------------------------------
__global__ void k_flag(const int* __restrict__ x32, int* __restrict__ flag) {
    __shared__ int red[256];
    const int t = threadIdx.x;
    int acc = 0;
    for (int k = t; k < 1024; k += 256)
        acc |= x32[2 * k + 1];
    red[t] = acc;
    __syncthreads();
    for (int s = 128; s > 0; s >>= 1) {
        if (t < s) red[t] |= red[t + s];
        __syncthreads();
    }
    if (t == 0) flag[0] = red[0];
}

__device__ __forceinline__ int x_at(const int* __restrict__ x32, int f, int idx) {
    return x32[f ? idx : 2 * idx];
}

__device__ __forceinline__ float sel5(const float p[5], int v) {
    float p_ = p[4];
    p_ = (v == 3) ? p[3] : p_;
    p_ = (v == 2) ? p[2] : p_;
    p_ = (v == 1) ? p[1] : p_;
    p_ = (v == 0) ? p[0] : p_;
    return p_;
}

// ---------------------------------------------------------------------------
// Kernel 1: P-tables + s gather (unchanged from R6).
// ---------------------------------------------------------------------------
__global__ void k_prep(const int* __restrict__ x32,
                       const float* __restrict__ emb,
                       const float* __restrict__ W,
                       const float* __restrict__ bias,
                       float* __restrict__ ws,
                       float* __restrict__ s_out) {
    const int bid = blockIdx.x;
    const int t   = threadIdx.x;
    if (bid < Vq) {
        const int v     = bid;
        const int which = t >> 7;
        const int e     = t & 127;
        float acc = which ? 0.0f : bias[e];
        const float* wrow = W + e * (2 * Dq) + which * Dq;
        const float* erow = emb + v * Dq;
        #pragma unroll 8
        for (int d = 0; d < Dq; ++d)
            acc += erow[d] * wrow[d];
        ws[which * (Vq * Dq) + v * Dq + e] = acc;
    } else {
        const int f    = ((const int*)ws)[WS_FLAG_OFF];
        const int sb   = bid - Vq;
        const int pair = t >> 4;
        const int dgrp = t & 15;
        const int bl   = sb * 16 + pair;
        const int v    = x_at(x32, f, bl);
        const float* src = emb + v * Dq + dgrp * 8;
        float*       dst = s_out + (size_t)bl * Dq + dgrp * 8;
        float4v a = *reinterpret_cast<const float4v*>(src);
        float4v b = *reinterpret_cast<const float4v*>(src + 4);
        *reinterpret_cast<float4v*>(dst)     = a;
        *reinterpret_cast<float4v*>(dst + 4) = b;
    }
}

// ---------------------------------------------------------------------------
// Kernel 1b (new): c1T[(b*128+e)*1024 + l1] = P1b[x[b,l1], e].
// 256 blocks (b,e) x 256 threads (4 l1 each). Runs after k_prep.
// ---------------------------------------------------------------------------
__global__ void k_c1(const int* __restrict__ x32,
                     float* __restrict__ ws) {
    const int bc = blockIdx.x;           // b*128 + e
    const int e  = bc & 127;
    const int b  = bc >> 7;
    const int t  = threadIdx.x;
    const int f  = ((const int*)ws)[WS_FLAG_OFF];
    float p1c[5];
    #pragma unroll
    for (int v = 0; v < 5; ++v) p1c[v] = ws[v * Dq + e];
    int vv[4];
    if (f) {
        int4v xv = *reinterpret_cast<const int4v*>(x32 + b * Lq + 4 * t);
        vv[0] = xv[0]; vv[1] = xv[1]; vv[2] = xv[2]; vv[3] = xv[3];
    } else {
        #pragma unroll
        for (int j = 0; j < 4; ++j) vv[j] = x_at(x32, 0, b * Lq + 4 * t + j);
    }
    float4v o;
    #pragma unroll
    for (int j = 0; j < 4; ++j) o[j] = sel5(p1c, vv[j]);
    *reinterpret_cast<float4v*>(ws + WS_C1_OFF + (size_t)bc * Lq + 4 * t) = o;
}

// ---------------------------------------------------------------------------
// Kernel 2 (R8): dependency-free store pipeline.
// Same layout/grid as R6 (2048 blocks, private 512-KB chunks, thread t ->
// cols 4t..4t+3, dense 1-KB wave stores). Change: c1 comes from c1T via a
// WAVE-UNIFORM index (blockIdx-only -> s_load), prefetched 32 rows at a
// time into registers; then 32 back-to-back stores whose data is already
// in regs. No LDS, no vector loads in the hot loop -> each wave keeps ~32
// stores in flight (was ~8 gated by ds_read lgkmcnt).
// ---------------------------------------------------------------------------
__global__ void __launch_bounds__(256) k_m(const int* __restrict__ x32,
                                           const float* __restrict__ ws,
                                           float* __restrict__ m_out) {
    constexpr int CH = Lq / 128;           // 8 chunks of 128 rows
    const int bid   = blockIdx.x;
    const int chunk = bid % CH;
    const int tmp   = bid / CH;
    const int e     = tmp % Dq;
    const int b     = tmp / Dq;
    const int t     = threadIdx.x;         // cols 4t..4t+3
    const int f     = ((const int*)ws)[WS_FLAG_OFF];

    // per-thread c2[4] (computed once)
    float p2c[5];
    #pragma unroll
    for (int v = 0; v < 5; ++v) p2c[v] = ws[Vq * Dq + v * Dq + e];
    int vv[4];
    if (f) {
        int4v xv = *reinterpret_cast<const int4v*>(x32 + b * Lq + 4 * t);
        vv[0] = xv[0]; vv[1] = xv[1]; vv[2] = xv[2]; vv[3] = xv[3];
    } else {
        #pragma unroll
        for (int j = 0; j < 4; ++j) vv[j] = x_at(x32, 0, b * Lq + 4 * t + j);
    }
    float c2[4];
    #pragma unroll
    for (int j = 0; j < 4; ++j) c2[j] = sel5(p2c, vv[j]);

    // wave-uniform c1 base (blockIdx-only index)
    const size_t row0 = (size_t)(b * Dq + e) * Lq + chunk * 128;
    const float* __restrict__ c1T = ws + WS_C1_OFF + row0;
    float* out_base = m_out + row0 * Lq + 4 * t;

    for (int c32 = 0; c32 < 4; ++c32) {
        // prefetch 32 c1 values (uniform addresses -> scalar loads)
        float c1v[32];
        #pragma unroll
        for (int k = 0; k < 32; ++k)
            c1v[k] = c1T[c32 * 32 + k];
        // 32 dependency-free dense stores
        #pragma unroll
        for (int k = 0; k < 32; ++k) {
            float4v o;
            #pragma unroll
            for (int j = 0; j < 4; ++j) o[j] = c1v[k] + c2[j];
            *reinterpret_cast<float4v*>(out_base + (size_t)(c32 * 32 + k) * Lq) = o;
        }
    }
}

extern "C" void kernel_launch(void* const* d_in, const int* in_sizes, int n_in,
                              void* d_out, int out_size, void* d_ws, size_t ws_size,
                              hipStream_t stream) {
    const int*   x32  = (const int*)d_in[0];
    const float* emb  = (const float*)d_in[1];
    const float* W    = (const float*)d_in[2];
    const float* bias = (const float*)d_in[3];
    float* out   = (float*)d_out;
    float* ws    = (float*)d_ws;
    float* s_out = out;
    float* m_out = out + (size_t)Bq * Lq * Dq;

    k_flag<<<1, 256, 0, stream>>>(x32, ((int*)ws) + WS_FLAG_OFF);
    k_prep<<<Vq + (Bq * Lq / 16), 256, 0, stream>>>(x32, emb, W, bias, ws, s_out);
    k_c1<<<Bq * Dq, 256, 0, stream>>>(x32, ws);
    k_m<<<Bq * Dq * (Lq / 128), 256, 0, stream>>>(x32, ws, m_out);
}